// Round 5
// baseline (203.617 us; speedup 1.0000x reference)
//
#include <hip/hip_runtime.h>
#include <hip/hip_bf16.h>

typedef __bf16 bf16x8 __attribute__((ext_vector_type(8)));
typedef float f32x4 __attribute__((ext_vector_type(4)));
typedef float f32x16 __attribute__((ext_vector_type(16)));

#define NB 2
#define NT 2048
#define ND 256
#define NH 8

__device__ inline __bf16 to_bf16(float f) {
  union { __hip_bfloat16 h; __bf16 b; } u;
  u.h = __float2bfloat16(f);
  return u.b;
}
__device__ inline float bf2f(__bf16 b) {
  union { __bf16 b; unsigned short s; } u; u.b = b;
  union { unsigned int i; float f; } v; v.i = ((unsigned int)u.s) << 16;
  return v.f;
}

typedef __attribute__((address_space(1))) const void g1void;
typedef __attribute__((address_space(3))) void l3void;

__device__ inline void gl_lds16(const void* g, void* l) {
  __builtin_amdgcn_global_load_lds((g1void*)g, (l3void*)l, 16, 0, 0);
}

// Stage 64x256 bf16 (32KB) tile into linear LDS; LDS chunk (row,c) holds
// global chunk (row, c ^ (row&31)).  chunk = 16B = 8 bf16.
__device__ inline void stage_tile64(const __bf16* gsrc, __bf16* lds, int tid) {
  int c = tid & 31;
  int rp = tid >> 5;  // 0..7
  const char* wave_uniform_base = (const char*)lds + (tid & ~63) * 16;
#pragma unroll
  for (int p = 0; p < 8; ++p) {
    int row = p * 8 + rp;
    const __bf16* g = gsrc + row * 256 + ((c ^ (row & 31)) << 3);
    gl_lds16((const void*)g, (void*)(wave_uniform_base + p * 4096));
  }
}

// ---------------------------------------------------------------------------
// convert: r'->bf16 Rb, E->bf16 Eb (layout-preserving, coalesced)
// ---------------------------------------------------------------------------
__global__ __launch_bounds__(256) void convert_kernel(
    const float* __restrict__ r, const float* __restrict__ E,
    __bf16* __restrict__ Rb, __bf16* __restrict__ Eb) {
  int idx = blockIdx.x * blockDim.x + threadIdx.x;
  const int nR = NB * NT * ND;
  const int nQ = NH * ND * ND;
  for (; idx < nR + nQ; idx += gridDim.x * blockDim.x) {
    if (idx < nR) Rb[idx] = to_bf16(r[idx]);
    else Eb[idx - nR] = to_bf16(E[idx - nR]);
  }
}

// ---------------------------------------------------------------------------
// transpose Q -> Qt[h][j][i] bf16, coalesced via LDS 32x32 tiles
// ---------------------------------------------------------------------------
__global__ __launch_bounds__(256) void transpose_q(
    const float* __restrict__ Q, __bf16* __restrict__ Qt) {
  __shared__ float T[32][33];
  int h = blockIdx.z;
  int i0 = blockIdx.y * 32, j0 = blockIdx.x * 32;
  int r = threadIdx.x >> 3, c4 = (threadIdx.x & 7) * 4;
  f32x4 v = *(const f32x4*)(Q + h * 65536 + (i0 + r) * 256 + j0 + c4);
#pragma unroll
  for (int j = 0; j < 4; ++j) T[r][c4 + j] = v[j];
  __syncthreads();
  __bf16* dst = Qt + h * 65536 + (j0 + r) * 256 + i0 + c4;
#pragma unroll
  for (int j = 0; j < 4; ++j) dst[j] = to_bf16(T[c4 + j][r]);
}

// ---------------------------------------------------------------------------
// gemm: C = A @ B^T  (both row-major K=256), 64x64 tile, 4 waves.
// ---------------------------------------------------------------------------
__global__ __launch_bounds__(256, 4) void gemm_abt(
    const __bf16* __restrict__ Abase, const __bf16* __restrict__ Bbase,
    __bf16* __restrict__ Cbase,
    int aStrideB, int aStrideH, int bStrideB, int bStrideH,
    int cStrideZ, int cRowStride) {
  __shared__ __bf16 Bs[64 * 256];

  int z = blockIdx.z;
  int bb = z >> 3, h = z & 7;
  const __bf16* A = Abase + (size_t)bb * aStrideB + (size_t)h * aStrideH;
  const __bf16* B = Bbase + (size_t)bb * bStrideB + (size_t)h * bStrideH;
  __bf16* C = Cbase + (size_t)z * cStrideZ;

  int m0 = blockIdx.x * 64, n0 = blockIdx.y * 64;
  int tid = threadIdx.x;
  int lane = tid & 63, w = tid >> 6;
  int l15 = lane & 15, lg = lane >> 4;

  stage_tile64(B + (size_t)n0 * 256, Bs, tid);

  bf16x8 af[8];
  const __bf16* arow = A + (size_t)(m0 + w * 16 + l15) * 256 + lg * 8;
#pragma unroll
  for (int ks = 0; ks < 8; ++ks) af[ks] = *(const bf16x8*)(arow + ks * 32);

  __syncthreads();

  f32x4 acc[4] = {};
#pragma unroll
  for (int ks = 0; ks < 8; ++ks) {
#pragma unroll
    for (int nt = 0; nt < 4; ++nt) {
      int row = nt * 16 + l15;
      int ch = (ks * 4 + lg) ^ (row & 31);
      bf16x8 bfr = *(const bf16x8*)(&Bs[row * 256 + ch * 8]);
      acc[nt] = __builtin_amdgcn_mfma_f32_16x16x32_bf16(af[ks], bfr, acc[nt], 0, 0, 0);
    }
  }
#pragma unroll
  for (int nt = 0; nt < 4; ++nt)
#pragma unroll
    for (int m = 0; m < 4; ++m)
      C[(size_t)(m0 + w * 16 + lg * 4 + m) * cRowStride + n0 + nt * 16 + l15] =
          to_bf16(acc[nt][m]);
}

// ---------------------------------------------------------------------------
// attn: block = (pair px, parity q, h, b). 32x32x16 MFMAs; A-frags in regs;
// partials to ws (no atomics) or atomic fallback.
// ---------------------------------------------------------------------------
__global__ __launch_bounds__(256, 2) void attn_kernel(
    const __bf16* __restrict__ Am, const __bf16* __restrict__ Rb,
    const __bf16* __restrict__ Vt, __bf16* __restrict__ partial,
    float* __restrict__ out, int use_partial) {
  __shared__ __bf16 Rk[2][64 * 256];  // 64KB dbuf, swizzled content
  __shared__ __bf16 Sl[64][68];       // S tile [t][u], padded

  int px = blockIdx.x >> 1, q = blockIdx.x & 1;
  int h = blockIdx.y, b = blockIdx.z;
  int z = b * NH + h;
  const __bf16* Amat = Am + (size_t)z * NT * ND;
  const __bf16* R = Rb + (size_t)b * NT * ND;
  const __bf16* V = Vt + (size_t)z * ND * NT;

  int tid = threadIdx.x;
  int lane = tid & 63, w = tid >> 6;
  int wt = w >> 1, wu = w & 1;  // wave grid 2x2; wu doubles as i-half for O
  int l31 = lane & 31, l5 = lane >> 5;

#pragma unroll 1
  for (int half = 0; half < 2; ++half) {
    int tt = half ? (31 - px) : px;
    int t0 = tt * 64;

    // A-frags: rows t0 + wt*32 + l31, 16 k-chunks of 8 (reused all iters)
    bf16x8 af[16];
    {
      const __bf16* arow = Amat + (size_t)(t0 + wt * 32 + l31) * ND + l5 * 8;
#pragma unroll
      for (int ks = 0; ks < 16; ++ks) af[ks] = *(const bf16x8*)(arow + ks * 16);
    }

    f32x16 acc[4] = {};  // O: 32t x 128i per wave (4 i-tiles of 32)

    if (tt >= q) {
      stage_tile64(R + (size_t)q * 64 * 256, &Rk[0][0], tid);
      asm volatile("s_waitcnt vmcnt(0)" ::: "memory");
      __builtin_amdgcn_s_barrier();

      int buf = 0;
#pragma unroll 1
      for (int ut = q; ut <= tt; ut += 2) {
        int u0 = ut * 64;
        if (ut + 2 <= tt)
          stage_tile64(R + (size_t)(ut + 2) * 64 * 256, &Rk[buf ^ 1][0], tid);

        // S = A @ R^T : one 32x32 tile per wave (wt, wu)
        const __bf16* Rcur = &Rk[buf][0];
        f32x16 s = {};
        int brow = wu * 32 + l31;
#pragma unroll
        for (int ks = 0; ks < 16; ++ks) {
          int ch = (ks * 2 + l5) ^ (brow & 31);
          bf16x8 bfr = *(const bf16x8*)(Rcur + brow * 256 + ch * 8);
          s = __builtin_amdgcn_mfma_f32_32x32x16_bf16(af[ks], bfr, s, 0, 0, 0);
        }
        // mask + write S to Sl[t][u] bf16
        int ucol = u0 + wu * 32 + l31;
#pragma unroll
        for (int rg = 0; rg < 16; ++rg) {
          int trow = (rg & 3) + 8 * (rg >> 2) + 4 * l5;  // within 32
          int tg = t0 + wt * 32 + trow;
          float v = (ucol <= tg) ? s[rg] : 0.0f;
          Sl[wt * 32 + trow][wu * 32 + l31] = to_bf16(v);
        }
        asm volatile("s_waitcnt lgkmcnt(0)" ::: "memory");
        __builtin_amdgcn_s_barrier();

        // O += S @ Vt : wave (wt, wu) -> 32t x 128i
        bf16x8 sf[4];
#pragma unroll
        for (int ks = 0; ks < 4; ++ks)
          sf[ks] = *(const bf16x8*)(&Sl[wt * 32 + l31][ks * 16 + l5 * 8]);
#pragma unroll
        for (int it = 0; it < 4; ++it) {
          const __bf16* vrow0 =
              V + (size_t)(wu * 128 + it * 32 + l31) * NT + u0 + l5 * 8;
#pragma unroll
          for (int ks = 0; ks < 4; ++ks) {
            bf16x8 vf = *(const bf16x8*)(vrow0 + ks * 16);
            acc[it] = __builtin_amdgcn_mfma_f32_32x32x16_bf16(sf[ks], vf, acc[it], 0, 0, 0);
          }
        }
        asm volatile("s_waitcnt vmcnt(0) lgkmcnt(0)" ::: "memory");
        __builtin_amdgcn_s_barrier();
        buf ^= 1;
      }
    }

    // epilogue: repack acc (bf16) into Rk[0] as [64][256], then coalesced out
    {
      __bf16* Ep = &Rk[0][0];
      __syncthreads();  // everyone done with Rk / Sl
#pragma unroll
      for (int it = 0; it < 4; ++it)
#pragma unroll
        for (int rg = 0; rg < 16; ++rg) {
          int trow = (rg & 3) + 8 * (rg >> 2) + 4 * l5;
          Ep[(wt * 32 + trow) * 256 + wu * 128 + it * 32 + l31] = to_bf16(acc[it][rg]);
        }
      __syncthreads();
      if (use_partial) {
        __bf16* Pdst = partial + ((size_t)(q * NH + h) * NB + b) * NT * ND +
                       (size_t)t0 * ND;
#pragma unroll
        for (int c = 0; c < 8; ++c) {
          int off = c * 256 + tid;  // 16B chunks
          *(bf16x8*)(Pdst + off * 8) = *(const bf16x8*)(Ep + off * 8);
        }
      } else {
        float* O = out + (size_t)b * NT * ND + (size_t)t0 * ND;
#pragma unroll
        for (int c = 0; c < 8; ++c) {
          int off = c * 256 + tid;
          bf16x8 vv = *(const bf16x8*)(Ep + off * 8);
#pragma unroll
          for (int e = 0; e < 8; ++e) atomicAdd(&O[off * 8 + e], bf2f(vv[e]));
        }
      }
      __syncthreads();  // Rk[0] free before next half's staging
    }
  }
}

// ---------------------------------------------------------------------------
// reduce: out[b][t][i] = sum over 16 (q,h) slices of partial
// layout: partial[(s*NB+b) * 524288 + t*256 + i], s = q*NH+h in [0,16)
// total out elems = NB*NT*ND = 1,048,576 -> 512 blocks x 256 thr x 8 elems
// ---------------------------------------------------------------------------
__global__ __launch_bounds__(256) void reduce_kernel(
    const __bf16* __restrict__ partial, float* __restrict__ out) {
  size_t gid = (size_t)blockIdx.x * 256 + threadIdx.x;
  size_t e = gid * 8;                 // elem index in [0, 1048576)
  int bb = (int)(e >> 19);            // batch: 524288 elems each
  size_t x = e & ((1u << 19) - 1);
  float sum[8] = {};
#pragma unroll
  for (int s = 0; s < 16; ++s) {
    bf16x8 v = *(const bf16x8*)(partial + (((size_t)(s * NB + bb)) << 19) + x);
#pragma unroll
    for (int j = 0; j < 8; ++j) sum[j] += bf2f(v[j]);
  }
  f32x4 lo = {sum[0], sum[1], sum[2], sum[3]};
  f32x4 hi = {sum[4], sum[5], sum[6], sum[7]};
  *(f32x4*)(out + e) = lo;
  *(f32x4*)(out + e + 4) = hi;
}

// ---------------------------------------------------------------------------
extern "C" void kernel_launch(void* const* d_in, const int* in_sizes, int n_in,
                              void* d_out, int out_size, void* d_ws, size_t ws_size,
                              hipStream_t stream) {
  const float* r = (const float*)d_in[0];
  const float* Q = (const float*)d_in[1];
  const float* E = (const float*)d_in[2];
  float* out = (float*)d_out;

  char* ws = (char*)d_ws;
  __bf16* Rb = (__bf16*)(ws);                 // 2 MB  [b][t][i]
  __bf16* Qt = (__bf16*)(ws + (2u << 20));    // 1 MB  [h][j][i]
  __bf16* Eb = (__bf16*)(ws + (3u << 20));    // 1 MB  [h][i][j]
  __bf16* Am = (__bf16*)(ws + (4u << 20));    // 16 MB [b][h][t][j]
  __bf16* Vt = (__bf16*)(ws + (20u << 20));   // 16 MB [b][h][i][u]
  __bf16* Pq = (__bf16*)(ws + (36u << 20));   // 32 MB [q*NH+h][b][t][i]
  int use_partial = (ws_size >= (72ull << 20)) ? 1 : 0;

  if (!use_partial)
    hipMemsetAsync(d_out, 0, (size_t)out_size * sizeof(float), stream);

  convert_kernel<<<1024, 256, 0, stream>>>(r, E, Rb, Eb);
  transpose_q<<<dim3(8, 8, 8), 256, 0, stream>>>(Q, Qt);

  // Am[b,h] = Rb[b] (2048x256) @ Qt[h]^T
  gemm_abt<<<dim3(32, 4, 16), 256, 0, stream>>>(
      Rb, Qt, Am, NT * ND, 0, 0, ND * ND, NT * ND, ND);

  // Vt[b,h] = (Eb[h] @ Rb[b]^T) -> [i][u], row stride NT
  gemm_abt<<<dim3(4, 32, 16), 256, 0, stream>>>(
      Eb, Rb, Vt, 0, ND * ND, NT * ND, 0, ND * NT, NT);

  attn_kernel<<<dim3(32, NH, NB), 256, 0, stream>>>(Am, Rb, Vt, Pq, out, use_partial);

  if (use_partial) reduce_kernel<<<512, 256, 0, stream>>>(Pq, out);
}

// Round 9
// 150.264 us; speedup vs baseline: 1.3551x; 1.3551x over previous
//
#include <hip/hip_runtime.h>
#include <hip/hip_bf16.h>

typedef __bf16 bf16x8 __attribute__((ext_vector_type(8)));
typedef float f32x4 __attribute__((ext_vector_type(4)));
typedef float f32x16 __attribute__((ext_vector_type(16)));

#define NB 2
#define NT 2048
#define ND 256
#define NH 8

__device__ inline __bf16 to_bf16(float f) {
  union { __hip_bfloat16 h; __bf16 b; } u;
  u.h = __float2bfloat16(f);
  return u.b;
}
__device__ inline float bf2f(__bf16 b) {
  union { __bf16 b; unsigned short s; } u; u.b = b;
  union { unsigned int i; float f; } v; v.i = ((unsigned int)u.s) << 16;
  return v.f;
}

typedef __attribute__((address_space(1))) const void g1void;
typedef __attribute__((address_space(3))) void l3void;

__device__ inline void gl_lds16(const void* g, void* l) {
  __builtin_amdgcn_global_load_lds((g1void*)g, (l3void*)l, 16, 0, 0);
}

// ---- 256-thread stager: 64x256 bf16 tile, LDS chunk (row,c) = global (row, c^(row&31))
__device__ inline void stage_tile64_t256(const __bf16* gsrc, __bf16* lds, int tid) {
  const char* wub = (const char*)lds + (tid & ~63) * 16;
#pragma unroll
  for (int p = 0; p < 8; ++p) {
    int lin = p * 256 + tid;
    int row = lin >> 5, c = lin & 31;
    const __bf16* g = gsrc + row * 256 + ((c ^ (row & 31)) << 3);
    gl_lds16((const void*)g, (void*)(wub + p * 4096));
  }
}

// ---- 512-thread stagers for attn ----
// R: 64 rows x 256 cols (row stride 256). chunk(row,c) = global (row, c^(row&31))
__device__ inline void stage_R64(const __bf16* gsrc, __bf16* lds, int w, int lane) {
#pragma unroll
  for (int p = 0; p < 4; ++p) {
    int lin = (p * 8 + w) * 64 + lane;
    int row = lin >> 5, c = lin & 31;
    const __bf16* g = gsrc + row * 256 + ((c ^ (row & 31)) << 3);
    gl_lds16((const void*)g, (void*)((char*)lds + (size_t)(p * 8 + w) * 1024));
  }
}
// V: 256 rows x 64 cols (row stride NT). chunk(row,c) = global (row, c^(row&7))
__device__ inline void stage_V64(const __bf16* gsrc, __bf16* lds, int w, int lane) {
#pragma unroll
  for (int p = 0; p < 4; ++p) {
    int lin = (p * 8 + w) * 64 + lane;
    int row = lin >> 3, c = lin & 7;
    const __bf16* g = gsrc + (size_t)row * NT + ((c ^ (row & 7)) << 3);
    gl_lds16((const void*)g, (void*)((char*)lds + (size_t)(p * 8 + w) * 1024));
  }
}

// ---------------------------------------------------------------------------
__global__ __launch_bounds__(256) void convert_kernel(
    const float* __restrict__ r, const float* __restrict__ E,
    __bf16* __restrict__ Rb, __bf16* __restrict__ Eb) {
  int idx = blockIdx.x * blockDim.x + threadIdx.x;
  const int nR = NB * NT * ND;
  const int nQ = NH * ND * ND;
  for (; idx < nR + nQ; idx += gridDim.x * blockDim.x) {
    if (idx < nR) Rb[idx] = to_bf16(r[idx]);
    else Eb[idx - nR] = to_bf16(E[idx - nR]);
  }
}

// ---------------------------------------------------------------------------
__global__ __launch_bounds__(256) void transpose_q(
    const float* __restrict__ Q, __bf16* __restrict__ Qt) {
  __shared__ float T[32][33];
  int h = blockIdx.z;
  int i0 = blockIdx.y * 32, j0 = blockIdx.x * 32;
  int r = threadIdx.x >> 3, c4 = (threadIdx.x & 7) * 4;
  f32x4 v = *(const f32x4*)(Q + h * 65536 + (i0 + r) * 256 + j0 + c4);
#pragma unroll
  for (int j = 0; j < 4; ++j) T[r][c4 + j] = v[j];
  __syncthreads();
  __bf16* dst = Qt + h * 65536 + (j0 + r) * 256 + i0 + c4;
#pragma unroll
  for (int j = 0; j < 4; ++j) dst[j] = to_bf16(T[c4 + j][r]);
}

// ---------------------------------------------------------------------------
// stage-1: both C = A @ B^T jobs in one launch. z<16: Am = Rb[b] @ Qt[h]^T;
// z>=16: Vt = Eb[h] @ Rb[b]^T.
// ---------------------------------------------------------------------------
__global__ __launch_bounds__(256, 4) void gemm_stage1(
    const __bf16* __restrict__ Rb, const __bf16* __restrict__ Qt,
    const __bf16* __restrict__ Eb, __bf16* __restrict__ Am,
    __bf16* __restrict__ Vt) {
  __shared__ __bf16 Bs[64 * 256];
  int z = blockIdx.z, x = blockIdx.x;
  const __bf16 *A, *B;
  __bf16* C;
  int m0, n0, cstride;
  if (z < 16) {
    int bb = z >> 3, h = z & 7;
    A = Rb + (size_t)bb * NT * ND;
    B = Qt + (size_t)h * ND * ND;
    C = Am + (size_t)z * NT * ND;
    m0 = (x & 31) * 64; n0 = (x >> 5) * 64; cstride = ND;
  } else {
    int zz = z - 16;
    int bb = zz >> 3, h = zz & 7;
    A = Eb + (size_t)h * ND * ND;
    B = Rb + (size_t)bb * NT * ND;
    C = Vt + (size_t)zz * ND * NT;
    m0 = (x & 3) * 64; n0 = (x >> 2) * 64; cstride = NT;
  }

  int tid = threadIdx.x;
  int lane = tid & 63, w = tid >> 6;
  int l15 = lane & 15, lg = lane >> 4;

  stage_tile64_t256(B + (size_t)n0 * 256, Bs, tid);

  bf16x8 af[8];
  const __bf16* arow = A + (size_t)(m0 + w * 16 + l15) * 256 + lg * 8;
#pragma unroll
  for (int ks = 0; ks < 8; ++ks) af[ks] = *(const bf16x8*)(arow + ks * 32);

  __syncthreads();

  f32x4 acc[4] = {};
#pragma unroll
  for (int ks = 0; ks < 8; ++ks) {
#pragma unroll
    for (int nt = 0; nt < 4; ++nt) {
      int row = nt * 16 + l15;
      int ch = (ks * 4 + lg) ^ (row & 31);
      bf16x8 bfr = *(const bf16x8*)(&Bs[row * 256 + ch * 8]);
      acc[nt] = __builtin_amdgcn_mfma_f32_16x16x32_bf16(af[ks], bfr, acc[nt], 0, 0, 0);
    }
  }
#pragma unroll
  for (int nt = 0; nt < 4; ++nt)
#pragma unroll
    for (int m = 0; m < 4; ++m)
      C[(size_t)(m0 + w * 16 + lg * 4 + m) * cstride + n0 + nt * 16 + l15] =
          to_bf16(acc[nt][m]);
}

// ---------------------------------------------------------------------------
// attn v2: 512 thr (8 waves), t-tile 128, 256 blocks (1/CU), exactly 17
// u-iters per block. R+V both LDS-staged (dbuf, swizzled). 32x32x16 MFMA.
// Wave (swt=w>>1, swu=w&1): S-tile t[swt*32..+32) x u[swu*32..+32);
// O: t[swt*32..+32) x i[swu*128..+128).
// ---------------------------------------------------------------------------
__global__ __launch_bounds__(512, 2) void attn_kernel(
    const __bf16* __restrict__ Am, const __bf16* __restrict__ Rb,
    const __bf16* __restrict__ Vt, __bf16* __restrict__ partial,
    float* __restrict__ out, int use_partial) {
  __shared__ __bf16 Rk[2][64 * 256];  // 64KB
  __shared__ __bf16 Vk[2][256 * 64];  // 64KB
  __shared__ __bf16 Sl[128 * 64];     // 16KB, chunk(row,c)=logical (row, c^(row&7))

  // XCD-clustered decode: blocks sharing (b,h) land on the same XCD (idx%8)
  int xx = blockIdx.x & 7, kk = blockIdx.x >> 3;
  int z = xx + 8 * (kk & 1);
  int local = kk >> 1;  // 0..15
  int px = local >> 1, q = local & 1;
  int b = z >> 3, h = z & 7;

  const __bf16* Amat = Am + (size_t)z * NT * ND;
  const __bf16* R = Rb + (size_t)b * NT * ND;
  const __bf16* V = Vt + (size_t)z * ND * NT;

  int tid = threadIdx.x;
  int w = tid >> 6, lane = tid & 63;
  int l31 = lane & 31, l5 = lane >> 5;
  int swt = w >> 1, swu = w & 1;

#pragma unroll 1
  for (int half = 0; half < 2; ++half) {
    int tt = half ? (15 - px) : px;
    int t0 = tt * 128;
    int ulast = 2 * tt + 1;

    // prologue staging first (overlaps with af loads)
    stage_R64(R + (size_t)q * 64 * 256, &Rk[0][0], w, lane);
    stage_V64(V + q * 64, &Vk[0][0], w, lane);

    // A-frags: rows t0 + swt*32 + l31 (resident all iters of this half)
    bf16x8 af[16];
    {
      const __bf16* arow = Amat + (size_t)(t0 + swt * 32 + l31) * ND + l5 * 8;
#pragma unroll
      for (int ks = 0; ks < 16; ++ks) af[ks] = *(const bf16x8*)(arow + ks * 16);
    }

    f32x16 acc[4] = {};

    asm volatile("s_waitcnt vmcnt(0)" ::: "memory");
    __builtin_amdgcn_s_barrier();

    int buf = 0;
#pragma unroll 1
    for (int ut = q; ut <= ulast; ut += 2) {
      int u0 = ut * 64;
      if (ut + 2 <= ulast) {
        stage_R64(R + (size_t)(ut + 2) * 64 * 256, &Rk[buf ^ 1][0], w, lane);
        stage_V64(V + (ut + 2) * 64, &Vk[buf ^ 1][0], w, lane);
      }

      // ---- S = A @ R^T (two independent 8-chains) ----
      const __bf16* Rcur = &Rk[buf][0];
      int bbase = (swu * 32 + l31) * 256;  // u-row; (row&31)==l31
      f32x16 s0 = {}, s1 = {};
#pragma unroll
      for (int ks = 0; ks < 8; ++ks) {
        bf16x8 bfr = *(const bf16x8*)(Rcur + bbase + (((ks * 2 + l5) ^ l31) << 3));
        s0 = __builtin_amdgcn_mfma_f32_32x32x16_bf16(af[ks], bfr, s0, 0, 0, 0);
      }
#pragma unroll
      for (int ks = 8; ks < 16; ++ks) {
        bf16x8 bfr = *(const bf16x8*)(Rcur + bbase + (((ks * 2 + l5) ^ l31) << 3));
        s1 = __builtin_amdgcn_mfma_f32_32x32x16_bf16(af[ks], bfr, s1, 0, 0, 0);
      }
      f32x16 s = s0 + s1;

      // ---- mask + write Sl (swizzled) ----
      int ucol = u0 + swu * 32 + l31;
      int cg = swu * 4 + (l31 >> 3);
#pragma unroll
      for (int rg = 0; rg < 16; ++rg) {
        int trow = (rg & 3) + 8 * (rg >> 2) + 4 * l5;
        int srow = swt * 32 + trow;
        float v = (ucol <= t0 + srow) ? s[rg] : 0.0f;
        Sl[srow * 64 + ((cg ^ (srow & 7)) << 3) + (l31 & 7)] = to_bf16(v);
      }
      asm volatile("s_waitcnt lgkmcnt(0)" ::: "memory");
      __builtin_amdgcn_s_barrier();

      // ---- O += S @ Vt ----
      bf16x8 sf[4];
      int srow2 = swt * 32 + l31;
#pragma unroll
      for (int ks = 0; ks < 4; ++ks) {
        int c = (ks * 2 + l5) ^ (srow2 & 7);
        sf[ks] = *(const bf16x8*)(Sl + srow2 * 64 + c * 8);
      }
      const __bf16* Vcur = &Vk[buf][0];
#pragma unroll
      for (int it = 0; it < 4; ++it) {
        int irow = swu * 128 + it * 32 + l31;
#pragma unroll
        for (int ks = 0; ks < 4; ++ks) {
          int c = (ks * 2 + l5) ^ (irow & 7);
          bf16x8 vf = *(const bf16x8*)(Vcur + irow * 64 + c * 8);
          acc[it] = __builtin_amdgcn_mfma_f32_32x32x16_bf16(sf[ks], vf, acc[it], 0, 0, 0);
        }
      }
      asm volatile("s_waitcnt vmcnt(0) lgkmcnt(0)" ::: "memory");
      __builtin_amdgcn_s_barrier();
      buf ^= 1;
    }

    // ---- epilogue: repack through LDS (Rk area = 64KB = 128x256 bf16) ----
    __syncthreads();
    __bf16* Ep = &Rk[0][0];
#pragma unroll
    for (int it = 0; it < 4; ++it)
#pragma unroll
      for (int rg = 0; rg < 16; ++rg) {
        int trow = (rg & 3) + 8 * (rg >> 2) + 4 * l5;
        Ep[(swt * 32 + trow) * 256 + swu * 128 + it * 32 + l31] = to_bf16(acc[it][rg]);
      }
    __syncthreads();
    if (use_partial) {
      __bf16* Pdst = partial + ((size_t)(q * NH + h) * NB + b) * NT * ND +
                     (size_t)t0 * ND;
#pragma unroll
      for (int c = 0; c < 8; ++c) {
        int off = c * 512 + tid;
        *(bf16x8*)(Pdst + off * 8) = *(const bf16x8*)(Ep + off * 8);
      }
    } else {
      float* O = out + (size_t)b * NT * ND + (size_t)t0 * ND;
#pragma unroll
      for (int c = 0; c < 8; ++c) {
        int off = c * 512 + tid;
        bf16x8 vv = *(const bf16x8*)(Ep + off * 8);
#pragma unroll
        for (int e = 0; e < 8; ++e) atomicAdd(&O[off * 8 + e], bf2f(vv[e]));
      }
    }
    __syncthreads();  // Rk free before next half's staging
  }
}

// ---------------------------------------------------------------------------
// reduce: out[b][t][i] = sum over 16 (q,h) slices; slice stride 524288 elems
// ---------------------------------------------------------------------------
__global__ __launch_bounds__(256) void reduce_kernel(
    const __bf16* __restrict__ partial, float* __restrict__ out) {
  size_t gid = (size_t)blockIdx.x * 256 + threadIdx.x;
  size_t e = gid * 8;                 // elem index in [0, 1048576)
  int bb = (int)(e >> 19);
  size_t x = e & ((1u << 19) - 1);
  float sum[8] = {};
#pragma unroll
  for (int s = 0; s < 16; ++s) {
    bf16x8 v = *(const bf16x8*)(partial + (((size_t)(s * NB + bb)) << 19) + x);
#pragma unroll
    for (int j = 0; j < 8; ++j) sum[j] += bf2f(v[j]);
  }
  f32x4 lo = {sum[0], sum[1], sum[2], sum[3]};
  f32x4 hi = {sum[4], sum[5], sum[6], sum[7]};
  *(f32x4*)(out + e) = lo;
  *(f32x4*)(out + e + 4) = hi;
}

// ---------------------------------------------------------------------------
extern "C" void kernel_launch(void* const* d_in, const int* in_sizes, int n_in,
                              void* d_out, int out_size, void* d_ws, size_t ws_size,
                              hipStream_t stream) {
  const float* r = (const float*)d_in[0];
  const float* Q = (const float*)d_in[1];
  const float* E = (const float*)d_in[2];
  float* out = (float*)d_out;

  char* ws = (char*)d_ws;
  __bf16* Rb = (__bf16*)(ws);                 // 2 MB  [b][t][i]
  __bf16* Qt = (__bf16*)(ws + (2u << 20));    // 1 MB  [h][j][i]
  __bf16* Eb = (__bf16*)(ws + (3u << 20));    // 1 MB  [h][i][j]
  __bf16* Am = (__bf16*)(ws + (4u << 20));    // 16 MB [b][h][t][j]
  __bf16* Vt = (__bf16*)(ws + (20u << 20));   // 16 MB [b][h][i][u]
  __bf16* Pq = (__bf16*)(ws + (36u << 20));   // 32 MB [q*NH+h][b][t][i]
  int use_partial = (ws_size >= (72ull << 20)) ? 1 : 0;

  if (!use_partial)
    hipMemsetAsync(d_out, 0, (size_t)out_size * sizeof(float), stream);

  convert_kernel<<<1024, 256, 0, stream>>>(r, E, Rb, Eb);
  transpose_q<<<dim3(8, 8, 8), 256, 0, stream>>>(Q, Qt);

  gemm_stage1<<<dim3(128, 1, 32), 256, 0, stream>>>(Rb, Qt, Eb, Am, Vt);

  attn_kernel<<<dim3(256), 512, 0, stream>>>(Am, Rb, Vt, Pq, out, use_partial);

  if (use_partial) reduce_kernel<<<512, 256, 0, stream>>>(Pq, out);
}